// Round 10
// baseline (189.398 us; speedup 1.0000x reference)
//
#include <hip/hip_runtime.h>

#define BB 64
#define SC 640
#define SN 128
#define DD 768
#define CODE_DEF 254
#define NL_DEF 126

typedef short bf16x8 __attribute__((ext_vector_type(8)));
typedef float f32x4 __attribute__((ext_vector_type(4)));

__device__ __forceinline__ unsigned short f2bf(float f) {
  unsigned u = __float_as_uint(f);
  u += 0x7fffu + ((u >> 16) & 1u);  // round-to-nearest-even
  return (unsigned short)(u >> 16);
}

// ---------------- K0: per-batch prep (64 blocks x 64) ------------------------
__global__ __launch_bounds__(64) void k0_prep(
    const int* __restrict__ code_ids, const int* __restrict__ nl_ids,
    const int* __restrict__ pos, const unsigned* __restrict__ attn_u32,
    int* __restrict__ nn, int* __restrict__ node_idx,
    int* __restrict__ len_code, int* __restrict__ len_nl,
    int* __restrict__ flag) {
  int b = blockIdx.x;
  int lane = threadIdx.x;  // 0..63
  int first = CODE_DEF;
  for (int c = 0; c < SC; c += 64) {
    bool is2 = code_ids[b * SC + c + lane] == 2;
    unsigned long long m = __ballot(is2);
    if (m) { first = c + __builtin_ctzll(m); break; }
  }
  int firstn = NL_DEF;
  for (int c = 0; c < SN; c += 64) {
    bool is2 = nl_ids[b * SN + c + lane] == 2;
    unsigned long long m = __ballot(is2);
    if (m) { firstn = c + __builtin_ctzll(m); break; }
  }
  int base = 0;
  for (int c = 0; c < SC; c += 64) {
    bool isn = pos[b * SC + c + lane] == 0;
    unsigned long long m = __ballot(isn);
    int pre = __popcll(m & ((1ull << lane) - 1ull));
    if (isn) node_idx[b * SC + base + pre] = c + lane;
    base += __popcll(m);
  }
  if (lane == 0) { nn[b] = base; len_code[b] = first; len_nl[b] = firstn; }
  if (b == 0) {
    int bad = 0;
    for (int i = lane; i < 1024; i += 64)
      if (attn_u32[i] > 1u) bad = 1;
    unsigned long long m = __ballot(bad);
    if (lane == 0) flag[0] = (m != 0ull) ? 1 : 0;
  }
}

// ---------------- K2: node-avg GEMM with INLINE mask build -------------------
// 64 nodes x 128 d per block; dbuf LDS; attn bits + token mask computed
// in the load phase. __launch_bounds__(256,3) pins VGPR<=170 so the 51KB-LDS
// occupancy (3 blocks/CU) isn't lost to register pressure.
__global__ __launch_bounds__(256, 3) void k2_mfma(
    const int* __restrict__ nn, const int* __restrict__ node_idx,
    const int* __restrict__ flag, const int* __restrict__ code_ids,
    const int* __restrict__ attn, const int* __restrict__ pos,
    const float* __restrict__ Wemb, float* __restrict__ codeh) {
  __shared__ unsigned short As[2][64 * 64];
  __shared__ unsigned short Bs[2][128 * 64];
  __shared__ int rowsidx[64];
  __shared__ int cid[SC];
  __shared__ unsigned long long tokm[10];
  __shared__ float cnts_l[64];
  int id = blockIdx.x;
  int b = id & 63;   // same-b -> same XCD (stride 64)
  int g = id >> 6;   // 0..23
  int nt = g & 3, dt = g >> 2;  // 4 node-tiles x 6 d-tiles
  int count = nn[b];
  if (nt * 64 >= count) return;
  int tid = threadIdx.x;
  const int lane = tid & 63, w = tid >> 6, wm = w >> 1, wn = w & 1;
  for (int i = tid; i < SC; i += 256) cid[i] = code_ids[b * SC + i];
  if (tid < 64) {
    int slot = nt * 64 + tid;
    rowsidx[tid] = (slot < count) ? node_idx[b * SC + slot] : -1;
  }
  if (w == 0) {  // token-mask bits, one ballot round per 64-t chunk
    for (int k = 0; k < 10; ++k) {
      unsigned long long m = __ballot(pos[b * SC + k * 64 + lane] >= 2);
      if (lane == 0) tokm[k] = m;
    }
  }
  __syncthreads();
  const int dcol = dt * 128;
  const int isu8 = flag[0];

  f32x4 acc[2][4];
#pragma unroll
  for (int m = 0; m < 2; ++m)
#pragma unroll
    for (int n = 0; n < 4; ++n) acc[m][n] = (f32x4){0.f, 0.f, 0.f, 0.f};

  const int r_a = tid >> 2, q_ = tid & 3;  // A: row 0..63, 16-t quarter 0..3
  const int nrow_a = rowsidx[r_a];
  const long arow = (nrow_a >= 0) ? ((long)b * SC + nrow_a) * SC : 0;
  const unsigned char* attn_u8 = (const unsigned char*)attn;
  int ptot = 0;
  int tg4[2], d0[2];
#pragma unroll
  for (int q = 0; q < 2; ++q) {
    int task = tid + 256 * q;
    tg4[q] = task >> 5;       // 0..15
    d0[q] = (task & 31) * 4;  // 0..124
  }

  f32x4 va[2][4];
  unsigned bits16;

#define LOADC(cc)                                                          \
  {                                                                        \
    unsigned tokq = (unsigned)((tokm[cc] >> (q_ * 16)) & 0xffffull);       \
    unsigned ab = 0;                                                       \
    if (nrow_a >= 0) {                                                     \
      if (isu8) {                                                          \
        uint4 v = *(const uint4*)(attn_u8 + arow + (cc) * 64 + q_ * 16);   \
        _Pragma("unroll") for (int j = 0; j < 4; ++j) {                    \
          ab |= (((v.x >> (8 * j)) & 0xffu) ? 1u : 0u) << j;               \
          ab |= (((v.y >> (8 * j)) & 0xffu) ? 1u : 0u) << (4 + j);         \
          ab |= (((v.z >> (8 * j)) & 0xffu) ? 1u : 0u) << (8 + j);         \
          ab |= (((v.w >> (8 * j)) & 0xffu) ? 1u : 0u) << (12 + j);        \
        }                                                                  \
      } else {                                                             \
        const int* ap = attn + arow + (cc) * 64 + q_ * 16;                 \
        _Pragma("unroll") for (int j = 0; j < 4; ++j) {                    \
          int4 v = *(const int4*)(ap + j * 4);                             \
          ab |= (v.x ? 1u : 0u) << (4 * j);                                \
          ab |= (v.y ? 1u : 0u) << (4 * j + 1);                            \
          ab |= (v.z ? 1u : 0u) << (4 * j + 2);                            \
          ab |= (v.w ? 1u : 0u) << (4 * j + 3);                            \
        }                                                                  \
      }                                                                    \
    }                                                                      \
    bits16 = ab & tokq;                                                    \
    ptot += __popc(bits16);                                                \
    _Pragma("unroll") for (int q = 0; q < 2; ++q)                          \
        _Pragma("unroll") for (int j = 0; j < 4; ++j) va[q][j] =           \
        *(const f32x4*)(Wemb +                                             \
                        (long)cid[(cc) * 64 + tg4[q] * 4 + j] * DD +       \
                        dcol + d0[q]);                                     \
  }

#define WRITEB(bf_)                                                        \
  {                                                                        \
    unsigned short* Ab = As[bf_];                                          \
    unsigned short* Bb = Bs[bf_];                                          \
    int tl = q_ * 16, sw = (r_a & 7) << 3;                                 \
    bf16x8 u0, u1;                                                         \
    _Pragma("unroll") for (int j = 0; j < 8; ++j) {                        \
      u0[j] = ((bits16 >> j) & 1u) ? (short)0x3F80 : (short)0;             \
      u1[j] = ((bits16 >> (8 + j)) & 1u) ? (short)0x3F80 : (short)0;       \
    }                                                                      \
    *(bf16x8*)(&Ab[r_a * 64 + (tl ^ sw)]) = u0;                            \
    *(bf16x8*)(&Ab[r_a * 64 + ((tl + 8) ^ sw)]) = u1;                      \
    _Pragma("unroll") for (int q = 0; q < 2; ++q)                          \
        _Pragma("unroll") for (int dj = 0; dj < 4; ++dj) {                 \
      int d = d0[q] + dj;                                                  \
      ushort4 u = {f2bf(va[q][0][dj]), f2bf(va[q][1][dj]),                 \
                   f2bf(va[q][2][dj]), f2bf(va[q][3][dj])};                \
      int s = ((((d >> 2) & 7) ^ ((d & 3) << 1)) << 3);                    \
      *(ushort4*)(&Bb[d * 64 + ((tg4[q] * 4) ^ s)]) = u;                   \
    }                                                                      \
  }

#define MFMAP(bf_)                                                         \
  {                                                                        \
    const unsigned short* Ab = As[bf_];                                    \
    const unsigned short* Bb = Bs[bf_];                                    \
    _Pragma("unroll") for (int ks = 0; ks < 2; ++ks) {                     \
      int kb = ks * 32 + (lane >> 4) * 8;                                  \
      bf16x8 af[2], bfv[4];                                                \
      _Pragma("unroll") for (int m = 0; m < 2; ++m) {                      \
        int rr = wm * 32 + m * 16 + (lane & 15);                           \
        af[m] = *(const bf16x8*)(&Ab[rr * 64 + (kb ^ ((rr & 7) << 3))]);   \
      }                                                                    \
      _Pragma("unroll") for (int n = 0; n < 4; ++n) {                      \
        int cc = wn * 64 + n * 16 + (lane & 15);                           \
        int s = ((((cc >> 2) & 7) ^ ((cc & 3) << 1)) << 3);                \
        bfv[n] = *(const bf16x8*)(&Bb[cc * 64 + (kb ^ s)]);                \
      }                                                                    \
      _Pragma("unroll") for (int m = 0; m < 2; ++m)                        \
          _Pragma("unroll") for (int n = 0; n < 4; ++n) acc[m][n] =        \
          __builtin_amdgcn_mfma_f32_16x16x32_bf16(af[m], bfv[n],           \
                                                  acc[m][n], 0, 0, 0);     \
    }                                                                      \
  }

  LOADC(0);
  WRITEB(0);
  __syncthreads();
  for (int c = 0; c < 10; ++c) {
    if (c < 9) LOADC(c + 1);
    MFMAP(c & 1);
    if (c < 9) WRITEB((c + 1) & 1);
    __syncthreads();
  }

  // counts: reduce 4 quarter-popcounts per row (lanes 4q..4q+3 share r_a)
  {
    int t4 = ptot + __shfl_xor(ptot, 1, 64);
    t4 += __shfl_xor(t4, 2, 64);
    if (q_ == 0) cnts_l[r_a] = (float)t4;
  }
  __syncthreads();

  // epilogue: divide by count, scatter raw avg to node rows
  float* outb = codeh + (long)b * SC * DD + dcol + wn * 64;
#pragma unroll
  for (int m = 0; m < 2; ++m) {
    int row0 = wm * 32 + m * 16 + ((lane >> 4) << 2);
#pragma unroll
    for (int rr2 = 0; rr2 < 4; ++rr2) {
      int slotr = row0 + rr2;
      int nr = rowsidx[slotr];
      if (nr < 0) continue;
      float cnt = cnts_l[slotr];
      float inv = (cnt > 0.f) ? 1.f / cnt : 0.f;
      float* orow = outb + (long)nr * DD;
#pragma unroll
      for (int n = 0; n < 4; ++n)
        orow[n * 16 + (lane & 15)] = acc[m][n][rr2] * inv;
    }
  }
#undef LOADC
#undef WRITEB
#undef MFMAP
}

// ---------------- K34: fused code-finish + nl branch (wave per row) ----------
#define CODE_BLOCKS (BB * SC / 4)
__global__ __launch_bounds__(256) void k34_fused(
    const int* __restrict__ code_ids, const int* __restrict__ pos,
    const float* __restrict__ Wemb, float* __restrict__ codeh,
    const int* __restrict__ roles, const float* __restrict__ role_table,
    const float* __restrict__ w_code, const float* __restrict__ b_code,
    const int* __restrict__ len_code, float* __restrict__ code_probs,
    const int* __restrict__ nl_ids, const float* __restrict__ w_nl,
    const float* __restrict__ b_nl, const int* __restrict__ len_nl,
    float* __restrict__ nlh, float* __restrict__ nl_probs) {
  int w = threadIdx.x >> 6, lane = threadIdx.x & 63;
  if (blockIdx.x < CODE_BLOCKS) {
    long row = (long)blockIdx.x * 4 + w;
    int b = (int)(row / SC), s = (int)(row % SC);
    float* rp = codeh + row * DD;
    const float* src = (pos[row] == 0) ? rp : (Wemb + (long)code_ids[row] * DD);
    f32x4 x[3];
#pragma unroll
    for (int j = 0; j < 3; ++j)
      x[j] = *(const f32x4*)(src + lane * 4 + j * 256);
    float ss = 0.f;
#pragma unroll
    for (int j = 0; j < 3; ++j)
#pragma unroll
      for (int e = 0; e < 4; ++e) ss += x[j][e] * x[j][e];
#pragma unroll
    for (int o = 32; o > 0; o >>= 1) ss += __shfl_xor(ss, o, 64);
    float inv = 1.f / fmaxf(sqrtf(ss), 1e-12f);
    const float* rt = role_table + (long)roles[row] * DD;
    float dot = 0.f;
#pragma unroll
    for (int j = 0; j < 3; ++j) {
      f32x4 r = *(const f32x4*)(rt + lane * 4 + j * 256);
      f32x4 wc = *(const f32x4*)(w_code + lane * 4 + j * 256);
      f32x4 y;
#pragma unroll
      for (int e = 0; e < 4; ++e) {
        y[e] = x[j][e] * inv;
        dot += (y[e] + r[e]) * wc[e];
      }
      *(f32x4*)(rp + lane * 4 + j * 256) = y;
    }
#pragma unroll
    for (int o = 32; o > 0; o >>= 1) dot += __shfl_xor(dot, o, 64);
    if (lane == 0) {
      float p = 1.f / (1.f + expf(-(dot + b_code[0])));
      code_probs[row] = (s < len_code[b]) ? p : 0.f;
    }
  } else {
    long row = (long)(blockIdx.x - CODE_BLOCKS) * 4 + w;
    int b = (int)(row / SN), s = (int)(row % SN);
    const float* src = Wemb + (long)nl_ids[row] * DD;
    f32x4 x[3];
#pragma unroll
    for (int j = 0; j < 3; ++j)
      x[j] = *(const f32x4*)(src + lane * 4 + j * 256);
    float ss = 0.f;
#pragma unroll
    for (int j = 0; j < 3; ++j)
#pragma unroll
      for (int e = 0; e < 4; ++e) ss += x[j][e] * x[j][e];
#pragma unroll
    for (int o = 32; o > 0; o >>= 1) ss += __shfl_xor(ss, o, 64);
    float inv = 1.f / fmaxf(sqrtf(ss), 1e-12f);
    float* o = nlh + row * DD;
    float dot = 0.f;
#pragma unroll
    for (int j = 0; j < 3; ++j) {
      f32x4 wn = *(const f32x4*)(w_nl + lane * 4 + j * 256);
      f32x4 y;
#pragma unroll
      for (int e = 0; e < 4; ++e) {
        y[e] = x[j][e] * inv;
        dot += y[e] * wn[e];
      }
      *(f32x4*)(o + lane * 4 + j * 256) = y;
    }
#pragma unroll
    for (int of = 32; of > 0; of >>= 1) dot += __shfl_xor(dot, of, 64);
    if (lane == 0) {
      float p = 1.f / (1.f + expf(-(dot + b_nl[0])));
      nl_probs[row] = (s < len_nl[b]) ? p : 0.f;
    }
  }
}

// ---------------- K5: sim via bf16 MFMA, 64x128 tiles, KC=128 ----------------
__global__ __launch_bounds__(256, 3) void k5_mfma(
    const float* __restrict__ nlh, const float* __restrict__ codeh,
    float* __restrict__ sim) {
  __shared__ unsigned short As[64 * 128];
  __shared__ unsigned short Bs[128 * 128];
  int id = blockIdx.x;
  int b = id & 63;
  int r = id >> 6;             // 0..9
  int nt = r % 2, ct = r / 2;  // nl half, code 128-tile
  int tid = threadIdx.x;
  int lane = tid & 63;
  int w = tid >> 6;
  int wm = w >> 1, wn = w & 1;  // wave: 32 nl x 64 code

  f32x4 acc[2][4];
#pragma unroll
  for (int m = 0; m < 2; ++m)
#pragma unroll
    for (int n = 0; n < 4; ++n) acc[m][n] = (f32x4){0.f, 0.f, 0.f, 0.f};

  const float* Ag = nlh + ((long)b * SN + nt * 64) * DD;
  const float* Bg = codeh + ((long)b * SC + ct * 128) * DD;

  for (int c = 0; c < DD / 128; ++c) {
#pragma unroll
    for (int it = 0; it < 8; ++it) {
      int i = tid + 256 * it;  // 0..2047
      int row = i >> 5, k0 = (i & 31) * 4;
      float4 va = *(const float4*)(Ag + (long)row * DD + c * 128 + k0);
      ushort4 ua = {f2bf(va.x), f2bf(va.y), f2bf(va.z), f2bf(va.w)};
      *(ushort4*)(&As[row * 128 + (k0 ^ ((row & 7) << 3))]) = ua;
    }
#pragma unroll
    for (int it = 0; it < 16; ++it) {
      int i = tid + 256 * it;  // 0..4095
      int row = i >> 5, k0 = (i & 31) * 4;
      float4 vb = *(const float4*)(Bg + (long)row * DD + c * 128 + k0);
      ushort4 ub = {f2bf(vb.x), f2bf(vb.y), f2bf(vb.z), f2bf(vb.w)};
      *(ushort4*)(&Bs[row * 128 + (k0 ^ ((row & 7) << 3))]) = ub;
    }
    __syncthreads();
#pragma unroll
    for (int ks = 0; ks < 4; ++ks) {
      int kb = ks * 32 + (lane >> 4) * 8;
      bf16x8 af[2], bfr[4];
#pragma unroll
      for (int m = 0; m < 2; ++m) {
        int rr = wm * 32 + m * 16 + (lane & 15);
        af[m] = *(const bf16x8*)(&As[rr * 128 + (kb ^ ((rr & 7) << 3))]);
      }
#pragma unroll
      for (int n = 0; n < 4; ++n) {
        int rr = wn * 64 + n * 16 + (lane & 15);
        bfr[n] = *(const bf16x8*)(&Bs[rr * 128 + (kb ^ ((rr & 7) << 3))]);
      }
#pragma unroll
      for (int m = 0; m < 2; ++m)
#pragma unroll
        for (int n = 0; n < 4; ++n)
          acc[m][n] = __builtin_amdgcn_mfma_f32_16x16x32_bf16(
              af[m], bfr[n], acc[m][n], 0, 0, 0);
    }
    __syncthreads();
  }
  long ob = ((long)b * SN + nt * 64) * SC + ct * 128;
#pragma unroll
  for (int m = 0; m < 2; ++m) {
    int row0 = wm * 32 + m * 16 + ((lane >> 4) << 2);
#pragma unroll
    for (int n = 0; n < 4; ++n) {
      int col = wn * 64 + n * 16 + (lane & 15);
#pragma unroll
      for (int rr = 0; rr < 4; ++rr)
        sim[ob + (long)(row0 + rr) * SC + col] = acc[m][n][rr];
    }
  }
}

// ---------------- launcher ---------------------------------------------------
extern "C" void kernel_launch(void* const* d_in, const int* in_sizes, int n_in,
                              void* d_out, int out_size, void* d_ws,
                              size_t ws_size, hipStream_t stream) {
  const int* code_ids = (const int*)d_in[0];
  const int* attn = (const int*)d_in[1];
  const int* pos = (const int*)d_in[2];
  const int* nl_ids = (const int*)d_in[3];
  const int* roles = (const int*)d_in[4];
  const float* Wemb = (const float*)d_in[5];
  const float* role_table = (const float*)d_in[6];
  const float* w_code = (const float*)d_in[7];
  const float* b_code = (const float*)d_in[8];
  const float* w_nl = (const float*)d_in[9];
  const float* b_nl = (const float*)d_in[10];

  float* out = (float*)d_out;
  float* codeh = out;                  // 64*640*768
  float* code_probs = out + 31457280;  // 64*640
  float* nlh = out + 31498240;         // 64*128*768
  float* nl_probs = out + 37789696;    // 64*128
  float* sim = out + 37797888;         // 64*128*640

  int* wsi = (int*)d_ws;
  int* nn = wsi;                        // 64
  int* node_idx = wsi + 64;             // 64*640
  int* len_code = node_idx + BB * SC;   // 64
  int* len_nl = len_code + 64;          // 64
  int* flag = len_nl + 64;              // 1

  k0_prep<<<BB, 64, 0, stream>>>(code_ids, nl_ids, pos, (const unsigned*)attn,
                                 nn, node_idx, len_code, len_nl, flag);
  k2_mfma<<<BB * 24, 256, 0, stream>>>(nn, node_idx, flag, code_ids, attn, pos,
                                       Wemb, codeh);
  k34_fused<<<CODE_BLOCKS + BB * SN / 4, 256, 0, stream>>>(
      code_ids, pos, Wemb, codeh, roles, role_table, w_code, b_code, len_code,
      code_probs, nl_ids, w_nl, b_nl, len_nl, nlh, nl_probs);
  k5_mfma<<<BB * 10, 256, 0, stream>>>(nlh, codeh, sim);
}

// Round 11
// 152.396 us; speedup vs baseline: 1.2428x; 1.2428x over previous
//
#include <hip/hip_runtime.h>

#define BB 64
#define SC 640
#define SN 128
#define DD 768
#define CODE_DEF 254
#define NL_DEF 126

typedef short bf16x8 __attribute__((ext_vector_type(8)));
typedef float f32x4 __attribute__((ext_vector_type(4)));

__device__ __forceinline__ unsigned short f2bf(float f) {
  unsigned u = __float_as_uint(f);
  u += 0x7fffu + ((u >> 16) & 1u);  // round-to-nearest-even
  return (unsigned short)(u >> 16);
}

// ---------------- K2: node-avg GEMM, fully self-sufficient -------------------
// Prologue (wave-split): w0 = node compaction for this nt-window; w1 = token
// bits; w2 = attn dtype detect; w3 (g==0) = eos lens for k34. Then the R9
// dbuf MFMA loop: 64 nodes x 128 d, inline attn-bit mask build.
// As: mask bf16 [64 node][64 t], swz elem^=(row&7)<<3.
// Bs: embT bf16 [128 d][64 t], swz elem^=(((d>>2)&7)^((d&3)<<1))<<3.
__global__ __launch_bounds__(256) void k2_mfma(
    const int* __restrict__ code_ids, const int* __restrict__ nl_ids,
    const int* __restrict__ attn, const int* __restrict__ pos,
    const float* __restrict__ Wemb, float* __restrict__ codeh,
    int* __restrict__ len_code, int* __restrict__ len_nl) {
  __shared__ unsigned short As[2][64 * 64];
  __shared__ unsigned short Bs[2][128 * 64];
  __shared__ int rowsidx[64];
  __shared__ int cid[SC];
  __shared__ unsigned long long tokm[10];
  __shared__ float cnts_l[64];
  __shared__ int cnt_s, flag_s;
  int id = blockIdx.x;
  int b = id & 63;   // same-b -> same XCD (stride 64)
  int g = id >> 6;   // 0..23
  int nt = g & 3, dt = g >> 2;  // 4 node-tiles x 6 d-tiles
  int tid = threadIdx.x;
  const int lane = tid & 63, w = tid >> 6, wm = w >> 1, wn = w & 1;
  for (int i = tid; i < SC; i += 256) cid[i] = code_ids[b * SC + i];
  if (tid < 64) rowsidx[tid] = -1;  // w0's own lanes, program-order safe
  if (w == 0) {  // node compaction, keep slots in [nt*64, nt*64+64)
    int base = 0;
    for (int c = 0; c < 10; ++c) {
      bool isn = pos[b * SC + c * 64 + lane] == 0;
      unsigned long long m = __ballot(isn);
      int pre = __popcll(m & ((1ull << lane) - 1ull));
      int slot = base + pre;
      if (isn && slot >= nt * 64 && slot < nt * 64 + 64)
        rowsidx[slot - nt * 64] = c * 64 + lane;
      base += __popcll(m);
    }
    if (lane == 0) cnt_s = base;
  } else if (w == 1) {  // token-mask bits
    for (int k = 0; k < 10; ++k) {
      unsigned long long m = __ballot(pos[b * SC + k * 64 + lane] >= 2);
      if (lane == 0) tokm[k] = m;
    }
  } else if (w == 2) {  // attn dtype detect (first 4KB, L2-hot)
    int bad = 0;
    for (int i = lane; i < 1024; i += 64)
      if (((const unsigned*)attn)[i] > 1u) bad = 1;
    unsigned long long m = __ballot(bad);
    if (lane == 0) flag_s = (m != 0ull) ? 1 : 0;
  } else if (g == 0) {  // w==3: eos lens for k34 (one block-set per batch)
    int first = CODE_DEF;
    for (int c = 0; c < SC; c += 64) {
      unsigned long long m = __ballot(code_ids[b * SC + c + lane] == 2);
      if (m) { first = c + __builtin_ctzll(m); break; }
    }
    int firstn = NL_DEF;
    for (int c = 0; c < SN; c += 64) {
      unsigned long long m = __ballot(nl_ids[b * SN + c + lane] == 2);
      if (m) { firstn = c + __builtin_ctzll(m); break; }
    }
    if (lane == 0) { len_code[b] = first; len_nl[b] = firstn; }
  }
  __syncthreads();
  const int count = cnt_s;
  if (nt * 64 >= count) return;
  const int dcol = dt * 128;
  const int isu8 = flag_s;

  f32x4 acc[2][4];
#pragma unroll
  for (int m = 0; m < 2; ++m)
#pragma unroll
    for (int n = 0; n < 4; ++n) acc[m][n] = (f32x4){0.f, 0.f, 0.f, 0.f};

  const int r_a = tid >> 2, q_ = tid & 3;  // A: row 0..63, 16-t quarter 0..3
  const int nrow_a = rowsidx[r_a];
  const long arow = (nrow_a >= 0) ? ((long)b * SC + nrow_a) * SC : 0;
  const unsigned char* attn_u8 = (const unsigned char*)attn;
  int ptot = 0;
  int tg4[2], d0[2];
#pragma unroll
  for (int q = 0; q < 2; ++q) {
    int task = tid + 256 * q;
    tg4[q] = task >> 5;       // 0..15
    d0[q] = (task & 31) * 4;  // 0..124
  }

  f32x4 va[2][4];
  unsigned bits16;

#define LOADC(cc)                                                          \
  {                                                                        \
    unsigned tokq = (unsigned)((tokm[cc] >> (q_ * 16)) & 0xffffull);       \
    unsigned ab = 0;                                                       \
    if (nrow_a >= 0) {                                                     \
      if (isu8) {                                                          \
        uint4 v = *(const uint4*)(attn_u8 + arow + (cc) * 64 + q_ * 16);   \
        _Pragma("unroll") for (int j = 0; j < 4; ++j) {                    \
          ab |= (((v.x >> (8 * j)) & 0xffu) ? 1u : 0u) << j;               \
          ab |= (((v.y >> (8 * j)) & 0xffu) ? 1u : 0u) << (4 + j);         \
          ab |= (((v.z >> (8 * j)) & 0xffu) ? 1u : 0u) << (8 + j);         \
          ab |= (((v.w >> (8 * j)) & 0xffu) ? 1u : 0u) << (12 + j);        \
        }                                                                  \
      } else {                                                             \
        const int* ap = attn + arow + (cc) * 64 + q_ * 16;                 \
        _Pragma("unroll") for (int j = 0; j < 4; ++j) {                    \
          int4 v = *(const int4*)(ap + j * 4);                             \
          ab |= (v.x ? 1u : 0u) << (4 * j);                                \
          ab |= (v.y ? 1u : 0u) << (4 * j + 1);                            \
          ab |= (v.z ? 1u : 0u) << (4 * j + 2);                            \
          ab |= (v.w ? 1u : 0u) << (4 * j + 3);                            \
        }                                                                  \
      }                                                                    \
    }                                                                      \
    bits16 = ab & tokq;                                                    \
    ptot += __popc(bits16);                                                \
    _Pragma("unroll") for (int q = 0; q < 2; ++q)                          \
        _Pragma("unroll") for (int j = 0; j < 4; ++j) va[q][j] =           \
        *(const f32x4*)(Wemb +                                             \
                        (long)cid[(cc) * 64 + tg4[q] * 4 + j] * DD +       \
                        dcol + d0[q]);                                     \
  }

#define WRITEB(bf_)                                                        \
  {                                                                        \
    unsigned short* Ab = As[bf_];                                          \
    unsigned short* Bb = Bs[bf_];                                          \
    int tl = q_ * 16, sw = (r_a & 7) << 3;                                 \
    bf16x8 u0, u1;                                                         \
    _Pragma("unroll") for (int j = 0; j < 8; ++j) {                        \
      u0[j] = ((bits16 >> j) & 1u) ? (short)0x3F80 : (short)0;             \
      u1[j] = ((bits16 >> (8 + j)) & 1u) ? (short)0x3F80 : (short)0;       \
    }                                                                      \
    *(bf16x8*)(&Ab[r_a * 64 + (tl ^ sw)]) = u0;                            \
    *(bf16x8*)(&Ab[r_a * 64 + ((tl + 8) ^ sw)]) = u1;                      \
    _Pragma("unroll") for (int q = 0; q < 2; ++q)                          \
        _Pragma("unroll") for (int dj = 0; dj < 4; ++dj) {                 \
      int d = d0[q] + dj;                                                  \
      ushort4 u = {f2bf(va[q][0][dj]), f2bf(va[q][1][dj]),                 \
                   f2bf(va[q][2][dj]), f2bf(va[q][3][dj])};                \
      int s = ((((d >> 2) & 7) ^ ((d & 3) << 1)) << 3);                    \
      *(ushort4*)(&Bb[d * 64 + ((tg4[q] * 4) ^ s)]) = u;                   \
    }                                                                      \
  }

#define MFMAP(bf_)                                                         \
  {                                                                        \
    const unsigned short* Ab = As[bf_];                                    \
    const unsigned short* Bb = Bs[bf_];                                    \
    _Pragma("unroll") for (int ks = 0; ks < 2; ++ks) {                     \
      int kb = ks * 32 + (lane >> 4) * 8;                                  \
      bf16x8 af[2], bfv[4];                                                \
      _Pragma("unroll") for (int m = 0; m < 2; ++m) {                      \
        int rr = wm * 32 + m * 16 + (lane & 15);                           \
        af[m] = *(const bf16x8*)(&Ab[rr * 64 + (kb ^ ((rr & 7) << 3))]);   \
      }                                                                    \
      _Pragma("unroll") for (int n = 0; n < 4; ++n) {                      \
        int cc = wn * 64 + n * 16 + (lane & 15);                           \
        int s = ((((cc >> 2) & 7) ^ ((cc & 3) << 1)) << 3);                \
        bfv[n] = *(const bf16x8*)(&Bb[cc * 64 + (kb ^ s)]);                \
      }                                                                    \
      _Pragma("unroll") for (int m = 0; m < 2; ++m)                        \
          _Pragma("unroll") for (int n = 0; n < 4; ++n) acc[m][n] =        \
          __builtin_amdgcn_mfma_f32_16x16x32_bf16(af[m], bfv[n],           \
                                                  acc[m][n], 0, 0, 0);     \
    }                                                                      \
  }

  LOADC(0);
  WRITEB(0);
  __syncthreads();
  for (int c = 0; c < 10; ++c) {
    if (c < 9) LOADC(c + 1);
    MFMAP(c & 1);
    if (c < 9) WRITEB((c + 1) & 1);
    __syncthreads();
  }

  // counts: reduce 4 quarter-popcounts per row (lanes 4q..4q+3 share r_a)
  {
    int t4 = ptot + __shfl_xor(ptot, 1, 64);
    t4 += __shfl_xor(t4, 2, 64);
    if (q_ == 0) cnts_l[r_a] = (float)t4;
  }
  __syncthreads();

  // epilogue: divide by count, scatter raw avg to node rows
  float* outb = codeh + (long)b * SC * DD + dcol + wn * 64;
#pragma unroll
  for (int m = 0; m < 2; ++m) {
    int row0 = wm * 32 + m * 16 + ((lane >> 4) << 2);
#pragma unroll
    for (int rr2 = 0; rr2 < 4; ++rr2) {
      int slotr = row0 + rr2;
      int nr = rowsidx[slotr];
      if (nr < 0) continue;
      float cnt = cnts_l[slotr];
      float inv = (cnt > 0.f) ? 1.f / cnt : 0.f;
      float* orow = outb + (long)nr * DD;
#pragma unroll
      for (int n = 0; n < 4; ++n)
        orow[n * 16 + (lane & 15)] = acc[m][n][rr2] * inv;
    }
  }
#undef LOADC
#undef WRITEB
#undef MFMAP
}

// ---------------- K34: fused code-finish + nl branch (wave per row) ----------
#define CODE_BLOCKS (BB * SC / 4)
__global__ __launch_bounds__(256) void k34_fused(
    const int* __restrict__ code_ids, const int* __restrict__ pos,
    const float* __restrict__ Wemb, float* __restrict__ codeh,
    const int* __restrict__ roles, const float* __restrict__ role_table,
    const float* __restrict__ w_code, const float* __restrict__ b_code,
    const int* __restrict__ len_code, float* __restrict__ code_probs,
    const int* __restrict__ nl_ids, const float* __restrict__ w_nl,
    const float* __restrict__ b_nl, const int* __restrict__ len_nl,
    float* __restrict__ nlh, float* __restrict__ nl_probs) {
  int w = threadIdx.x >> 6, lane = threadIdx.x & 63;
  if (blockIdx.x < CODE_BLOCKS) {
    long row = (long)blockIdx.x * 4 + w;
    int b = (int)(row / SC), s = (int)(row % SC);
    float* rp = codeh + row * DD;
    const float* src = (pos[row] == 0) ? rp : (Wemb + (long)code_ids[row] * DD);
    f32x4 x[3];
#pragma unroll
    for (int j = 0; j < 3; ++j)
      x[j] = *(const f32x4*)(src + lane * 4 + j * 256);
    float ss = 0.f;
#pragma unroll
    for (int j = 0; j < 3; ++j)
#pragma unroll
      for (int e = 0; e < 4; ++e) ss += x[j][e] * x[j][e];
#pragma unroll
    for (int o = 32; o > 0; o >>= 1) ss += __shfl_xor(ss, o, 64);
    float inv = 1.f / fmaxf(sqrtf(ss), 1e-12f);
    const float* rt = role_table + (long)roles[row] * DD;
    float dot = 0.f;
#pragma unroll
    for (int j = 0; j < 3; ++j) {
      f32x4 r = *(const f32x4*)(rt + lane * 4 + j * 256);
      f32x4 wc = *(const f32x4*)(w_code + lane * 4 + j * 256);
      f32x4 y;
#pragma unroll
      for (int e = 0; e < 4; ++e) {
        y[e] = x[j][e] * inv;
        dot += (y[e] + r[e]) * wc[e];
      }
      *(f32x4*)(rp + lane * 4 + j * 256) = y;
    }
#pragma unroll
    for (int o = 32; o > 0; o >>= 1) dot += __shfl_xor(dot, o, 64);
    if (lane == 0) {
      float p = 1.f / (1.f + expf(-(dot + b_code[0])));
      code_probs[row] = (s < len_code[b]) ? p : 0.f;
    }
  } else {
    long row = (long)(blockIdx.x - CODE_BLOCKS) * 4 + w;
    int b = (int)(row / SN), s = (int)(row % SN);
    const float* src = Wemb + (long)nl_ids[row] * DD;
    f32x4 x[3];
#pragma unroll
    for (int j = 0; j < 3; ++j)
      x[j] = *(const f32x4*)(src + lane * 4 + j * 256);
    float ss = 0.f;
#pragma unroll
    for (int j = 0; j < 3; ++j)
#pragma unroll
      for (int e = 0; e < 4; ++e) ss += x[j][e] * x[j][e];
#pragma unroll
    for (int o = 32; o > 0; o >>= 1) ss += __shfl_xor(ss, o, 64);
    float inv = 1.f / fmaxf(sqrtf(ss), 1e-12f);
    float* o = nlh + row * DD;
    float dot = 0.f;
#pragma unroll
    for (int j = 0; j < 3; ++j) {
      f32x4 wn = *(const f32x4*)(w_nl + lane * 4 + j * 256);
      f32x4 y;
#pragma unroll
      for (int e = 0; e < 4; ++e) {
        y[e] = x[j][e] * inv;
        dot += y[e] * wn[e];
      }
      *(f32x4*)(o + lane * 4 + j * 256) = y;
    }
#pragma unroll
    for (int of = 32; of > 0; of >>= 1) dot += __shfl_xor(dot, of, 64);
    if (lane == 0) {
      float p = 1.f / (1.f + expf(-(dot + b_nl[0])));
      nl_probs[row] = (s < len_nl[b]) ? p : 0.f;
    }
  }
}

// ---------------- K5: sim via bf16 MFMA, 64x128 tiles, KC=64 (R9 proven) -----
__global__ __launch_bounds__(256) void k5_mfma(const float* __restrict__ nlh,
                                               const float* __restrict__ codeh,
                                               float* __restrict__ sim) {
  __shared__ unsigned short As[64 * 64];
  __shared__ unsigned short Bs[128 * 64];
  int id = blockIdx.x;
  int b = id & 63;
  int r = id >> 6;             // 0..9
  int nt = r % 2, ct = r / 2;  // nl half, code 128-tile
  int tid = threadIdx.x;
  int lane = tid & 63;
  int w = tid >> 6;
  int wm = w >> 1, wn = w & 1;  // wave: 32 nl x 64 code

  f32x4 acc[2][4];
#pragma unroll
  for (int m = 0; m < 2; ++m)
#pragma unroll
    for (int n = 0; n < 4; ++n) acc[m][n] = (f32x4){0.f, 0.f, 0.f, 0.f};

  const float* Ag = nlh + ((long)b * SN + nt * 64) * DD;
  const float* Bg = codeh + ((long)b * SC + ct * 128) * DD;

  for (int c = 0; c < DD / 64; ++c) {
#pragma unroll
    for (int it = 0; it < 4; ++it) {
      int i = tid + 256 * it;  // 0..1023
      int row = i >> 4, k0 = (i & 15) * 4;
      float4 va = *(const float4*)(Ag + (long)row * DD + c * 64 + k0);
      ushort4 ua = {f2bf(va.x), f2bf(va.y), f2bf(va.z), f2bf(va.w)};
      *(ushort4*)(&As[row * 64 + (k0 ^ ((row & 7) << 3))]) = ua;
    }
#pragma unroll
    for (int it = 0; it < 8; ++it) {
      int i = tid + 256 * it;  // 0..2047
      int row = i >> 4, k0 = (i & 15) * 4;
      float4 vb = *(const float4*)(Bg + (long)row * DD + c * 64 + k0);
      ushort4 ub = {f2bf(vb.x), f2bf(vb.y), f2bf(vb.z), f2bf(vb.w)};
      *(ushort4*)(&Bs[row * 64 + (k0 ^ ((row & 7) << 3))]) = ub;
    }
    __syncthreads();
#pragma unroll
    for (int ks = 0; ks < 2; ++ks) {
      int kb = ks * 32 + (lane >> 4) * 8;
      bf16x8 af[2], bfr[4];
#pragma unroll
      for (int m = 0; m < 2; ++m) {
        int rr = wm * 32 + m * 16 + (lane & 15);
        af[m] = *(const bf16x8*)(&As[rr * 64 + (kb ^ ((rr & 7) << 3))]);
      }
#pragma unroll
      for (int n = 0; n < 4; ++n) {
        int rr = wn * 64 + n * 16 + (lane & 15);
        bfr[n] = *(const bf16x8*)(&Bs[rr * 64 + (kb ^ ((rr & 7) << 3))]);
      }
#pragma unroll
      for (int m = 0; m < 2; ++m)
#pragma unroll
        for (int n = 0; n < 4; ++n)
          acc[m][n] = __builtin_amdgcn_mfma_f32_16x16x32_bf16(
              af[m], bfr[n], acc[m][n], 0, 0, 0);
    }
    __syncthreads();
  }
  long ob = ((long)b * SN + nt * 64) * SC + ct * 128;
#pragma unroll
  for (int m = 0; m < 2; ++m) {
    int row0 = wm * 32 + m * 16 + ((lane >> 4) << 2);
#pragma unroll
    for (int n = 0; n < 4; ++n) {
      int col = wn * 64 + n * 16 + (lane & 15);
#pragma unroll
      for (int rr = 0; rr < 4; ++rr)
        sim[ob + (long)(row0 + rr) * SC + col] = acc[m][n][rr];
    }
  }
}

// ---------------- launcher ---------------------------------------------------
extern "C" void kernel_launch(void* const* d_in, const int* in_sizes, int n_in,
                              void* d_out, int out_size, void* d_ws,
                              size_t ws_size, hipStream_t stream) {
  const int* code_ids = (const int*)d_in[0];
  const int* attn = (const int*)d_in[1];
  const int* pos = (const int*)d_in[2];
  const int* nl_ids = (const int*)d_in[3];
  const int* roles = (const int*)d_in[4];
  const float* Wemb = (const float*)d_in[5];
  const float* role_table = (const float*)d_in[6];
  const float* w_code = (const float*)d_in[7];
  const float* b_code = (const float*)d_in[8];
  const float* w_nl = (const float*)d_in[9];
  const float* b_nl = (const float*)d_in[10];

  float* out = (float*)d_out;
  float* codeh = out;                  // 64*640*768
  float* code_probs = out + 31457280;  // 64*640
  float* nlh = out + 31498240;         // 64*128*768
  float* nl_probs = out + 37789696;    // 64*128
  float* sim = out + 37797888;         // 64*128*640

  int* wsi = (int*)d_ws;
  int* len_code = wsi;       // 64
  int* len_nl = wsi + 64;    // 64

  k2_mfma<<<BB * 24, 256, 0, stream>>>(code_ids, nl_ids, attn, pos, Wemb,
                                       codeh, len_code, len_nl);
  k34_fused<<<CODE_BLOCKS + BB * SN / 4, 256, 0, stream>>>(
      code_ids, pos, Wemb, codeh, roles, role_table, w_code, b_code, len_code,
      code_probs, nl_ids, w_nl, b_nl, len_nl, nlh, nl_probs);
  k5_mfma<<<BB * 10, 256, 0, stream>>>(nlh, codeh, sim);
}